// Round 2
// baseline (114.062 us; speedup 1.0000x reference)
//
#include <hip/hip_runtime.h>
#include <hip/hip_fp16.h>

// ApproxConv2d via 256x256 LUT (approximate multiplier).
// out[b,o,y,x] = sum_{c,ky,kx} lut[ qx[b,c,y+ky-1,x+kx-1]*256 + qw[o,c,ky,kx] ] + bias[o]
// qx/qw = clip(rint(v*64), -128, 127) + 128; out-of-bounds taps -> qx=128 -> lut 0.
//
// v2: fp16 LUT band (30.5 KiB vs 62.5 KiB) + half-image blocks (grid 1024)
// -> 4 blocks/CU, 16 waves/CU (50% occupancy) to hide LDS gather latency.
// Random-row band gathers (~300M) are the fundamental cost; qw columns are
// lane-uniform and tightly banded (w ~ 0.1*N(0,1) -> width < 61 per o).

#define BW 61          // band width in LUT columns (odd -> spreads LDS banks)
#define NT 256

__device__ __forceinline__ int quantize(float v) {
    // clip(rint(v*64), -128, 127) + 128, round-half-to-even matches jnp.round
    int q = (int)rintf(v * 64.0f);
    q = q < -128 ? -128 : q;
    q = q > 127 ? 127 : q;
    return q + 128;
}

__global__ __launch_bounds__(NT, 4)
void approxconv2d_kernel(const float* __restrict__ x,
                         const float* __restrict__ w,
                         const float* __restrict__ bias,
                         const float* __restrict__ lut,
                         float* __restrict__ out)
{
    __shared__ __half band[256 * BW];        // 30.5 KiB fp16 band
    __shared__ unsigned int plane[180];      // 18 rows x 40 bytes (halo-padded qx)
    __shared__ unsigned char qwrow[576];
    __shared__ int s_min;

    const int tid = threadIdx.x;
    const int bid = blockIdx.x;
    const int b = bid >> 7;                  // batch
    const int o = (bid >> 1) & 63;           // output channel
    const int h = bid & 1;                   // image half (rows 0-15 / 16-31)

    if (tid == 0) s_min = 255;
    for (int i = tid; i < 180; i += NT) plane[i] = 0x80808080u;  // q=128 -> 0
    __syncthreads();

    int lmin = 255;
    for (int i = tid; i < 576; i += NT) {
        int q = quantize(w[o * 576 + i]);
        qwrow[i] = (unsigned char)q;
        lmin = lmin < q ? lmin : q;
    }
    atomicMin(&s_min, lmin);
    __syncthreads();

    int cmin = s_min;
    if (cmin > 256 - BW) cmin = 256 - BW;

    // stage fp16 band: band[qx*BW + cc] = lut[qx*256 + cmin + cc]
    for (int i = tid; i < 256 * BW; i += NT) {
        int qx = i / BW;
        int cc = i - qx * BW;
        band[i] = __float2half(lut[(qx << 8) + cmin + cc]);
    }

    const int yl = tid >> 4;                 // local row 0..15
    const int xp = tid & 15;
    const int x0 = xp << 1;                  // 2 pixels per thread
    const int yg = (h << 4) + yl;            // global output row

    // inner-boundary halo row is real data; outer halo stays 128 (padding)
    const int halo_g  = h ? 15 : 16;         // global row to stage
    const int halo_pr = h ? 0  : 17;         // plane row it lands in

    float acc0 = 0.f, acc1 = 0.f;
    const float* xb = x + (size_t)b * 64 * 1024;
    unsigned char* pb = (unsigned char*)plane;

    for (int c = 0; c < 64; ++c) {
        __syncthreads();                     // band ready / prior reads done
        const float* xc = xb + c * 1024;
        float2 xv = *(const float2*)(xc + yg * 32 + x0);
        int qa = quantize(xv.x), qb = quantize(xv.y);
        int wb = (yl + 1) * 40 + x0 + 1;
        pb[wb]     = (unsigned char)qa;
        pb[wb + 1] = (unsigned char)qb;
        if (tid < 32) {
            int qh = quantize(xc[halo_g * 32 + tid]);
            pb[halo_pr * 40 + 1 + tid] = (unsigned char)qh;
        }
        __syncthreads();

        const unsigned char* qwp = qwrow + c * 9;
        #pragma unroll
        for (int ky = 0; ky < 3; ++ky) {
            int w0 = (yl + ky) * 10 + (x0 >> 2);
            unsigned int a = plane[w0];
            unsigned int v;
            if (x0 & 2) v = (a >> 16) | (plane[w0 + 1] << 16);
            else        v = a;
            int e0 = (int)(v & 255u), e1 = (int)((v >> 8) & 255u);
            int e2 = (int)((v >> 16) & 255u), e3 = (int)(v >> 24);
            int p0 = e0 * BW, p1 = e1 * BW, p2 = e2 * BW, p3 = e3 * BW;
            #pragma unroll
            for (int kx = 0; kx < 3; ++kx) {
                int cq = (int)qwp[ky * 3 + kx];
                int cc = cq - cmin;
                int pa  = (kx == 0 ? p0 : (kx == 1 ? p1 : p2));
                int pbx = (kx == 0 ? p1 : (kx == 1 ? p2 : p3));
                if ((unsigned)cc < (unsigned)BW) {   // wave-uniform (cq is uniform)
                    acc0 += __half2float(band[pa + cc]);
                    acc1 += __half2float(band[pbx + cc]);
                } else {                             // ~never: outside band
                    int ea = (kx == 0 ? e0 : (kx == 1 ? e1 : e2));
                    int eb = (kx == 0 ? e1 : (kx == 1 ? e2 : e3));
                    acc0 += lut[(ea << 8) + cq];
                    acc1 += lut[(eb << 8) + cq];
                }
            }
        }
    }

    float bo = bias[o];
    float2 r; r.x = acc0 + bo; r.y = acc1 + bo;
    *(float2*)(out + ((size_t)b * 64 + o) * 1024 + yg * 32 + x0) = r;
}

extern "C" void kernel_launch(void* const* d_in, const int* in_sizes, int n_in,
                              void* d_out, int out_size, void* d_ws, size_t ws_size,
                              hipStream_t stream) {
    const float* x    = (const float*)d_in[0];
    const float* wgt  = (const float*)d_in[1];
    const float* bias = (const float*)d_in[2];
    const float* lut  = (const float*)d_in[3];
    float* out = (float*)d_out;

    // 1024 blocks = 8 batches x 64 channels x 2 image halves; ~32.5 KiB LDS
    // -> 4 blocks/CU resident = 16 waves/CU (50% occupancy)
    hipLaunchKernelGGL(approxconv2d_kernel, dim3(1024), dim3(NT), 0, stream,
                       x, wgt, bias, lut, out);
}

// Round 3
// 77.143 us; speedup vs baseline: 1.4786x; 1.4786x over previous
//
#include <hip/hip_runtime.h>
#include <hip/hip_fp16.h>

// ApproxConv2d via 256x256 LUT (approximate multiplier).
// out[b,o,y,x] = sum_{c,ky,kx} lut[ qx(b,c,y+ky-1,x+kx-1)*256 + qw(o,c,ky,kx) ] + bias[o]
// qx/qw = clip(rint(v*64), -128, 127) + 128; padding -> qx=128 -> lut row 128 values*0 -> 0.
//
// v3: tap-row table. Pre-kernel builds T[o][c][qx][slot] fp16 (slot = ky*4+kx,
// row stride 24B) so the main kernel fetches the 3 kx-taps of one (input px, ky)
// with ONE ds_read_b64 (2.0 MACs/DS-instr vs 1.0 for random b32 gathers, and
// better bank-start spread). T_c (6 KiB) is double-buffered in LDS, staged with
// issue-early/write-late (T14). Random-gather conflicts (~4.1 cyc/instr in v1/v2)
// were the measured cost; this halves DS instruction count on the same pipe.

#define NT 256
#define BANDW 65   // pre-kernel band width (stride 65 -> conflict-free lane=row reads)

__device__ __forceinline__ int quantize(float v) {
    // clip(rint(v*64), -128, 127) + 128; rintf = round-half-to-even = jnp.round
    int q = (int)rintf(v * 64.0f);
    q = q < -128 ? -128 : q;
    q = q > 127 ? 127 : q;
    return q + 128;
}

// ---------------- pre-kernel: T[o][c][qx][12] fp16, row stride 24B --------
// block = (o, qx-quarter); lanes sweep qx (conflict-free band reads).
__global__ __launch_bounds__(NT, 2)
void build_T_kernel(const float* __restrict__ w, const float* __restrict__ lut,
                    __half* __restrict__ T)
{
    __shared__ float band[64 * BANDW];       // local qx rows x 65 cols
    __shared__ unsigned char qwrow[576];
    __shared__ int s_min;

    const int tid = threadIdx.x;
    const int o  = blockIdx.x >> 2;
    const int qq = (blockIdx.x & 3) << 6;    // qx base of this quarter

    if (tid == 0) s_min = 255;
    __syncthreads();
    int lmin = 255;
    for (int i = tid; i < 576; i += NT) {
        int q = quantize(w[o * 576 + i]);
        qwrow[i] = (unsigned char)q;
        lmin = lmin < q ? lmin : q;
    }
    atomicMin(&s_min, lmin);
    __syncthreads();
    int cmin = s_min;
    if (cmin > 256 - BANDW) cmin = 256 - BANDW;

    for (int i = tid; i < 64 * BANDW; i += NT) {
        int r = i / BANDW, cc = i - r * BANDW;
        int col = cmin + cc; col = col > 255 ? 255 : col;
        band[i] = lut[(qq + r) * 256 + col];
    }
    __syncthreads();

    const int lane = tid & 63;               // local qx row
    const int wv = tid >> 6;
    for (int it = 0; it < 16; ++it) {
        int c = it * 4 + wv;
        int qx = qq + lane;
        const unsigned char* qp = qwrow + c * 9;
        unsigned int wd[6];
        #pragma unroll
        for (int ky = 0; ky < 3; ++ky) {
            unsigned short hh[3];
            #pragma unroll
            for (int kx = 0; kx < 3; ++kx) {
                int cq = (int)qp[ky * 3 + kx];
                int cc = cq - cmin;
                float v;
                if ((unsigned)cc < (unsigned)BANDW) v = band[lane * BANDW + cc];
                else v = lut[qx * 256 + cq];          // rare outlier (wave-uniform)
                hh[kx] = __half_as_ushort(__float2half(v));
            }
            wd[ky * 2 + 0] = (unsigned int)hh[0] | ((unsigned int)hh[1] << 16);
            wd[ky * 2 + 1] = (unsigned int)hh[2];     // slot3 = pad (0 in hi16)
        }
        size_t row = (size_t)(o * 64 + c) * 256 + qx;
        uint2* p = (uint2*)((char*)T + row * 24);
        p[0] = make_uint2(wd[0], wd[1]);
        p[1] = make_uint2(wd[2], wd[3]);
        p[2] = make_uint2(wd[4], wd[5]);
    }
}

// ---------------- main kernel: block = (b,o), 4-px strips ------------------
__device__ __forceinline__ float h_lo(unsigned int u) {
    return __half2float(__ushort_as_half((unsigned short)(u & 0xffffu)));
}
__device__ __forceinline__ float h_hi(unsigned int u) {
    return __half2float(__ushort_as_half((unsigned short)(u >> 16)));
}

__global__ __launch_bounds__(NT, 2)
void approx_main_kernel(const float* __restrict__ x, const __half* __restrict__ T,
                        const float* __restrict__ bias, float* __restrict__ out)
{
    __shared__ __align__(16) char Ts[2][6144];      // T_c double buffer (fp16 rows)
    __shared__ unsigned int plane[2][340];          // 34 rows x 40B qx plane, dbuf

    const int tid = threadIdx.x;
    const int bid = blockIdx.x;
    const int b = bid >> 6, o = bid & 63;

    for (int i = tid; i < 680; i += NT) ((unsigned int*)plane)[i] = 0x80808080u;

    const char* Tg = (const char*)T + (size_t)o * 64 * 6144;
    const float* xb = x + (size_t)b * 65536;
    const int y = tid >> 3, xs = tid & 7, x0 = xs << 2;

    // prologue: loads for c=0
    uint4 ta = *(const uint4*)(Tg + tid * 16);
    uint4 tb;
    if (tid < 128) tb = *(const uint4*)(Tg + 4096 + tid * 16);
    float4 xv = *(const float4*)(xb + y * 32 + x0);

    float acc0 = 0.f, acc1 = 0.f, acc2 = 0.f, acc3 = 0.f;

    for (int c = 0; c < 64; ++c) {
        const int cb = c & 1;
        // write-late: stage T_c and plane_c (loads were issued last iter)
        *(uint4*)&Ts[cb][tid * 16] = ta;
        if (tid < 128) *(uint4*)&Ts[cb][4096 + tid * 16] = tb;
        unsigned char* pb = (unsigned char*)plane[cb];
        int wb = (y + 1) * 40 + x0 + 1;
        pb[wb]     = (unsigned char)quantize(xv.x);
        pb[wb + 1] = (unsigned char)quantize(xv.y);
        pb[wb + 2] = (unsigned char)quantize(xv.z);
        pb[wb + 3] = (unsigned char)quantize(xv.w);
        __syncthreads();

        // issue-early: next channel's loads (vmcnt-waited at next iter's writes)
        if (c < 63) {
            const char* Tn = Tg + (c + 1) * 6144;
            ta = *(const uint4*)(Tn + tid * 16);
            if (tid < 128) tb = *(const uint4*)(Tn + 4096 + tid * 16);
            xv = *(const float4*)(xb + (c + 1) * 1024 + y * 32 + x0);
        }

        // compute channel c: per ky, 6 input pixels -> 6 ds_read_b64, 12 MACs
        const unsigned int* pl = plane[cb];
        const char* Tb = Ts[cb];
        #pragma unroll
        for (int ky = 0; ky < 3; ++ky) {
            unsigned int w0 = pl[(y + ky) * 10 + xs];
            unsigned int w1 = pl[(y + ky) * 10 + xs + 1];
            int e0 = (int)(w0 & 255u), e1 = (int)((w0 >> 8) & 255u);
            int e2 = (int)((w0 >> 16) & 255u), e3 = (int)(w0 >> 24);
            int e4 = (int)(w1 & 255u), e5 = (int)((w1 >> 8) & 255u);
            const char* Tk = Tb + ky * 8;
            uint2 v0 = *(const uint2*)(Tk + e0 * 24);
            uint2 v1 = *(const uint2*)(Tk + e1 * 24);
            uint2 v2 = *(const uint2*)(Tk + e2 * 24);
            uint2 v3 = *(const uint2*)(Tk + e3 * 24);
            uint2 v4 = *(const uint2*)(Tk + e4 * 24);
            uint2 v5 = *(const uint2*)(Tk + e5 * 24);
            // row e_j feeds output p with tap kx = j - p (kx0=lo(x),kx1=hi(x),kx2=lo(y))
            acc0 += h_lo(v0.x);
            acc1 += h_lo(v1.x);  acc0 += h_hi(v1.x);
            acc2 += h_lo(v2.x);  acc1 += h_hi(v2.x);  acc0 += h_lo(v2.y);
            acc3 += h_lo(v3.x);  acc2 += h_hi(v3.x);  acc1 += h_lo(v3.y);
            acc3 += h_hi(v4.x);  acc2 += h_lo(v4.y);
            acc3 += h_lo(v5.y);
        }
    }

    float bo = bias[o];
    float4 r;
    r.x = acc0 + bo; r.y = acc1 + bo; r.z = acc2 + bo; r.w = acc3 + bo;
    *(float4*)(out + (size_t)bid * 1024 + y * 32 + x0) = r;
}

// ---------------- fallback (proven v1, 98us): used if ws too small --------
#define BW1 61
__global__ __launch_bounds__(NT, 2)
void approxconv2d_v1(const float* __restrict__ x,
                     const float* __restrict__ w,
                     const float* __restrict__ bias,
                     const float* __restrict__ lut,
                     float* __restrict__ out)
{
    __shared__ float band[256 * BW1];
    __shared__ unsigned int plane[340];
    __shared__ unsigned char qwrow[576];
    __shared__ int s_min;

    const int tid = threadIdx.x;
    const int bid = blockIdx.x;
    const int b = bid >> 6;
    const int o = bid & 63;

    if (tid == 0) s_min = 255;
    for (int i = tid; i < 340; i += NT) plane[i] = 0x80808080u;
    __syncthreads();

    int lmin = 255;
    for (int i = tid; i < 576; i += NT) {
        int q = quantize(w[o * 576 + i]);
        qwrow[i] = (unsigned char)q;
        lmin = lmin < q ? lmin : q;
    }
    atomicMin(&s_min, lmin);
    __syncthreads();

    int cmin = s_min;
    if (cmin > 256 - BW1) cmin = 256 - BW1;

    for (int i = tid; i < 256 * BW1; i += NT) {
        int qx = i / BW1;
        int cc = i - qx * BW1;
        band[i] = lut[(qx << 8) + cmin + cc];
    }

    const int y  = tid >> 3;
    const int xq = tid & 7;
    const int x0 = xq << 2;

    float acc0 = 0.f, acc1 = 0.f, acc2 = 0.f, acc3 = 0.f;
    const float* xb = x + (size_t)b * 64 * 1024;
    unsigned char* pb = (unsigned char*)plane;

    for (int c = 0; c < 64; ++c) {
        __syncthreads();
        float4 xv = *(const float4*)(xb + c * 1024 + y * 32 + x0);
        int qa = quantize(xv.x), qb = quantize(xv.y);
        int qc = quantize(xv.z), qd = quantize(xv.w);
        int wbase = (y + 1) * 40 + x0 + 1;
        pb[wbase + 0] = (unsigned char)qa;
        pb[wbase + 1] = (unsigned char)qb;
        pb[wbase + 2] = (unsigned char)qc;
        pb[wbase + 3] = (unsigned char)qd;
        __syncthreads();

        const unsigned char* qwp = qwrow + c * 9;
        #pragma unroll
        for (int ky = 0; ky < 3; ++ky) {
            int ro = (y + ky) * 10 + xq;
            unsigned int r0 = plane[ro];
            unsigned int r1 = plane[ro + 1];
            int ee[6];
            ee[0] = (int)(r0 & 255u);
            ee[1] = (int)((r0 >> 8) & 255u);
            ee[2] = (int)((r0 >> 16) & 255u);
            ee[3] = (int)(r0 >> 24);
            ee[4] = (int)(r1 & 255u);
            ee[5] = (int)((r1 >> 8) & 255u);
            int pp[6];
            #pragma unroll
            for (int t = 0; t < 6; ++t) pp[t] = ee[t] * BW1;
            #pragma unroll
            for (int kx = 0; kx < 3; ++kx) {
                int cq = (int)qwp[ky * 3 + kx];
                int cc = cq - cmin;
                if ((unsigned)cc < (unsigned)BW1) {
                    acc0 += band[pp[kx + 0] + cc];
                    acc1 += band[pp[kx + 1] + cc];
                    acc2 += band[pp[kx + 2] + cc];
                    acc3 += band[pp[kx + 3] + cc];
                } else {
                    acc0 += lut[(ee[kx + 0] << 8) + cq];
                    acc1 += lut[(ee[kx + 1] << 8) + cq];
                    acc2 += lut[(ee[kx + 2] << 8) + cq];
                    acc3 += lut[(ee[kx + 3] << 8) + cq];
                }
            }
        }
    }

    float bo = bias[o];
    float4 r;
    r.x = acc0 + bo; r.y = acc1 + bo; r.z = acc2 + bo; r.w = acc3 + bo;
    *(float4*)(out + (size_t)bid * 1024 + y * 32 + x0) = r;
}

extern "C" void kernel_launch(void* const* d_in, const int* in_sizes, int n_in,
                              void* d_out, int out_size, void* d_ws, size_t ws_size,
                              hipStream_t stream) {
    const float* x    = (const float*)d_in[0];
    const float* wgt  = (const float*)d_in[1];
    const float* bias = (const float*)d_in[2];
    const float* lut  = (const float*)d_in[3];
    float* out = (float*)d_out;

    const size_t T_BYTES = (size_t)64 * 64 * 256 * 24;   // 25,165,824
    if (ws_size >= T_BYTES) {
        hipLaunchKernelGGL(build_T_kernel, dim3(256), dim3(NT), 0, stream,
                           wgt, lut, (__half*)d_ws);
        hipLaunchKernelGGL(approx_main_kernel, dim3(512), dim3(NT), 0, stream,
                           x, (const __half*)d_ws, bias, out);
    } else {
        hipLaunchKernelGGL(approxconv2d_v1, dim3(512), dim3(NT), 0, stream,
                           x, wgt, bias, lut, out);
    }
}

// Round 4
// 76.797 us; speedup vs baseline: 1.4852x; 1.0045x over previous
//
#include <hip/hip_runtime.h>
#include <hip/hip_fp16.h>

// ApproxConv2d via 256x256 LUT (approximate multiplier).
// out[b,o,y,x] = sum_{c,ky,kx} lut[ qx(b,c,y+ky-1,x+kx-1)*256 + qw(o,c,ky,kx) ] + bias[o]
// qx/qw = clip(rint(v*64), -128, 127) + 128; padding -> qx=128 -> lut row 128 = 0.
//
// v4: o-PAIR tap table. T[pair][c][qx] row = 48B = 3 ky x 16B, where 16B =
// [o0: h(x0)|h(x1), h(x2)|0][o1: h(x0)|h(x1), h(x2)|0] (fp16 taps).
// Main kernel: lane pairs split the o's (even lane o0 b64 half, odd o1);
// per (pixel,ky) one b64/b32 read feeds up to 3 MACs for one o while plane
// reads, plane writes, and x loads amortize over 2 output channels.
// T_c (12KB) staged via global_load_lds width=16, double-buffered.
// Grid keyed so same-pair blocks share an XCD's L2 (bid%8 = pair%8).

#define NT 256

__device__ __forceinline__ int quantize(float v) {
    // clip(rint(v*64), -128, 127) + 128; rintf = round-half-to-even = jnp.round
    int q = (int)rintf(v * 64.0f);
    q = q < -128 ? -128 : q;
    q = q > 127 ? 127 : q;
    return q + 128;
}

__device__ __forceinline__ float flo(unsigned int u) {
    return __half2float(__ushort_as_half((unsigned short)(u & 0xffffu)));
}
__device__ __forceinline__ float fhi(unsigned int u) {
    return __half2float(__ushort_as_half((unsigned short)(u >> 16)));
}

__device__ __forceinline__ void gll16(const void* g, void* l) {
    __builtin_amdgcn_global_load_lds(
        (const __attribute__((address_space(1))) unsigned int*)g,
        (__attribute__((address_space(3))) unsigned int*)l, 16, 0, 0);
}

// -------- build: T[pair][c][qx] 48B rows, full-width LUT band (no outliers) --
__global__ __launch_bounds__(NT, 2)
void build_T2(const float* __restrict__ w, const float* __restrict__ lut,
              unsigned int* __restrict__ T)
{
    __shared__ float band[32 * 257];        // 32 lut rows, +1 pad -> conflict-free
    __shared__ unsigned char qw2[2][576];

    const int tid = threadIdx.x;
    const int pair = blockIdx.x >> 3;       // 0..31
    const int qq = (blockIdx.x & 7) << 5;   // qx slice base (32 rows)

    for (int i = tid; i < 1152; i += NT) {
        int os = i >= 576;
        int idx = i - os * 576;
        qw2[os][idx] = (unsigned char)quantize(w[(pair * 2 + os) * 576 + idx]);
    }
    for (int i = tid; i < 32 * 256; i += NT) {
        int r = i >> 8, c2 = i & 255;
        band[r * 257 + c2] = lut[qq * 256 + i];
    }
    __syncthreads();

    // 64 c x 32 qxl x 3 ky = 6144 uint4 items; consecutive idx -> coalesced stores
    for (int it = 0; it < 24; ++it) {
        int idx = it * NT + tid;
        int c = idx / 96;
        int rem = idx - c * 96;
        int qxl = rem / 3;
        int ky = rem - qxl * 3;
        const float* brow = band + qxl * 257;
        unsigned int d[4];
        #pragma unroll
        for (int os = 0; os < 2; ++os) {
            const unsigned char* qp = &qw2[os][c * 9 + ky * 3];
            unsigned int h0 = __half_as_ushort(__float2half(brow[qp[0]]));
            unsigned int h1 = __half_as_ushort(__float2half(brow[qp[1]]));
            unsigned int h2 = __half_as_ushort(__float2half(brow[qp[2]]));
            d[os * 2]     = h0 | (h1 << 16);
            d[os * 2 + 1] = h2;
        }
        size_t off = ((size_t)(pair * 64 + c) * 256 + qq + qxl) * 48 + ky * 16;
        *(uint4*)((char*)T + off) = make_uint4(d[0], d[1], d[2], d[3]);
    }
}

// -------- main: block = (pair, b, half); lane-pair o-split, 4px strips ------
__global__ __launch_bounds__(NT, 2)
void approx_main(const float* __restrict__ x, const unsigned int* __restrict__ T,
                 const float* __restrict__ bias, float* __restrict__ out)
{
    __shared__ __align__(16) unsigned char Ts[2][12288];  // T_c double buffer
    __shared__ unsigned int plane[2][180];                // 18 rows x 40B qx plane

    const int tid = threadIdx.x;
    const int bid = blockIdx.x;
    // bid%8 keys the XCD; same pair -> same slot -> shared L2 for its table
    const int xslot = bid & 7;
    const int jj = bid >> 3;                 // 0..63
    const int pair = xslot + ((jj & 3) << 3);
    const int bh = jj >> 2;                  // 0..15
    const int b = bh >> 1;
    const int h = bh & 1;

    const int osub = tid & 1;
    const int s = tid >> 1;                  // strip 0..127
    const int yl = s >> 3;                   // 0..15
    const int x0 = (s & 7) << 2;             // strip base col
    const int yg = (h << 4) + yl;
    const int o = pair * 2 + osub;
    const int wid = tid >> 6, lane = tid & 63;

    const char* Tg = (const char*)T + (size_t)pair * 64 * 12288;
    const float* xb = x + (size_t)b * 65536;

    const int halo_g  = h ? 15 : 16;         // global input row staged as halo
    const int halo_pr = h ? 0  : 17;         // plane row it lands in

    for (int i = tid; i < 360; i += NT) ((unsigned int*)plane)[i] = 0x80808080u;

    // prologue: prefetch c=0 (T via global_load_lds, x via regs)
    {
        const char* src = Tg + wid * 1024 + lane * 16;
        unsigned char* dst = &Ts[0][wid * 1024];
        gll16(src, dst);
        gll16(src + 4096, dst + 4096);
        gll16(src + 8192, dst + 8192);
    }
    float2 xv = *(const float2*)(xb + yg * 32 + x0 + osub * 2);
    float xh = (tid < 32) ? xb[halo_g * 32 + tid] : 0.f;

    __syncthreads();   // plane init complete

    float acc0 = 0.f, acc1 = 0.f, acc2 = 0.f, acc3 = 0.f;

    for (int c = 0; c < 64; ++c) {
        const int cb = c & 1;
        // write-late: plane[cb] from prefetched regs
        unsigned char* pbyte = (unsigned char*)plane[cb];
        unsigned short pk = (unsigned short)(quantize(xv.x) | (quantize(xv.y) << 8));
        *(unsigned short*)(pbyte + (yl + 1) * 40 + 2 + x0 + osub * 2) = pk;
        if (tid < 32) pbyte[halo_pr * 40 + 2 + tid] = (unsigned char)quantize(xh);
        __syncthreads();   // drains gll(c -> Ts[cb]) + makes plane[cb] visible

        // issue-early: c+1 prefetch overlaps compute of c
        if (c < 63) {
            const char* src = Tg + (c + 1) * 12288 + wid * 1024 + lane * 16;
            unsigned char* dst = &Ts[cb ^ 1][wid * 1024];
            gll16(src, dst);
            gll16(src + 4096, dst + 4096);
            gll16(src + 8192, dst + 8192);
            xv = *(const float2*)(xb + (c + 1) * 1024 + yg * 32 + x0 + osub * 2);
            if (tid < 32) xh = xb[(c + 1) * 1024 + halo_g * 32 + tid];
        }

        const unsigned int* pl = plane[cb];
        const char* Tb = (const char*)&Ts[cb][0] + osub * 8;  // this lane's o half
        #pragma unroll
        for (int ky = 0; ky < 3; ++ky) {
            unsigned int u0 = pl[(yl + ky) * 10 + (x0 >> 2)];
            unsigned int u1 = pl[(yl + ky) * 10 + (x0 >> 2) + 1];
            // 6 qx bytes e_j = input cols x0-1 .. x0+4 (plane is +2 shifted)
            int e0 = (int)((u0 >> 8) & 255u), e1 = (int)((u0 >> 16) & 255u);
            int e2 = (int)(u0 >> 24),         e3 = (int)(u1 & 255u);
            int e4 = (int)((u1 >> 8) & 255u), e5 = (int)((u1 >> 16) & 255u);
            const int kyo = ky * 16;
            // row e_j: tap kx feeds acc_{j-kx} (0<=j-kx<=3); halves: lo=x0,hi=x1,lo2=x2
            unsigned int r0 = *(const unsigned int*)(Tb + e0 * 48 + kyo);
            acc0 += flo(r0);
            uint2 r1 = *(const uint2*)(Tb + e1 * 48 + kyo);
            acc1 += flo(r1.x); acc0 += fhi(r1.x);
            uint2 r2 = *(const uint2*)(Tb + e2 * 48 + kyo);
            acc2 += flo(r2.x); acc1 += fhi(r2.x); acc0 += flo(r2.y);
            uint2 r3 = *(const uint2*)(Tb + e3 * 48 + kyo);
            acc3 += flo(r3.x); acc2 += fhi(r3.x); acc1 += flo(r3.y);
            uint2 r4 = *(const uint2*)(Tb + e4 * 48 + kyo);
            acc3 += fhi(r4.x); acc2 += flo(r4.y);
            unsigned int r5 = *(const unsigned int*)(Tb + e5 * 48 + kyo + 4);
            acc3 += flo(r5);
        }
    }

    float bo = bias[o];
    float4 r;
    r.x = acc0 + bo; r.y = acc1 + bo; r.z = acc2 + bo; r.w = acc3 + bo;
    *(float4*)(out + ((size_t)b * 64 + o) * 1024 + yg * 32 + x0) = r;
}

// -------- fallback (proven v1, 98us): used if ws too small ------------------
#define BW1 61
__global__ __launch_bounds__(NT, 2)
void approxconv2d_v1(const float* __restrict__ x,
                     const float* __restrict__ w,
                     const float* __restrict__ bias,
                     const float* __restrict__ lut,
                     float* __restrict__ out)
{
    __shared__ float band[256 * BW1];
    __shared__ unsigned int plane[340];
    __shared__ unsigned char qwrow[576];
    __shared__ int s_min;

    const int tid = threadIdx.x;
    const int bid = blockIdx.x;
    const int b = bid >> 6;
    const int o = bid & 63;

    if (tid == 0) s_min = 255;
    for (int i = tid; i < 340; i += NT) plane[i] = 0x80808080u;
    __syncthreads();

    int lmin = 255;
    for (int i = tid; i < 576; i += NT) {
        int q = quantize(w[o * 576 + i]);
        qwrow[i] = (unsigned char)q;
        lmin = lmin < q ? lmin : q;
    }
    atomicMin(&s_min, lmin);
    __syncthreads();

    int cmin = s_min;
    if (cmin > 256 - BW1) cmin = 256 - BW1;

    for (int i = tid; i < 256 * BW1; i += NT) {
        int qx = i / BW1;
        int cc = i - qx * BW1;
        band[i] = lut[(qx << 8) + cmin + cc];
    }

    const int y  = tid >> 3;
    const int xq = tid & 7;
    const int x0 = xq << 2;

    float acc0 = 0.f, acc1 = 0.f, acc2 = 0.f, acc3 = 0.f;
    const float* xb = x + (size_t)b * 64 * 1024;
    unsigned char* pb = (unsigned char*)plane;

    for (int c = 0; c < 64; ++c) {
        __syncthreads();
        float4 xv = *(const float4*)(xb + c * 1024 + y * 32 + x0);
        int qa = quantize(xv.x), qb = quantize(xv.y);
        int qc = quantize(xv.z), qd = quantize(xv.w);
        int wbase = (y + 1) * 40 + x0 + 1;
        pb[wbase + 0] = (unsigned char)qa;
        pb[wbase + 1] = (unsigned char)qb;
        pb[wbase + 2] = (unsigned char)qc;
        pb[wbase + 3] = (unsigned char)qd;
        __syncthreads();

        const unsigned char* qwp = qwrow + c * 9;
        #pragma unroll
        for (int ky = 0; ky < 3; ++ky) {
            int ro = (y + ky) * 10 + xq;
            unsigned int r0 = plane[ro];
            unsigned int r1 = plane[ro + 1];
            int ee[6];
            ee[0] = (int)(r0 & 255u);
            ee[1] = (int)((r0 >> 8) & 255u);
            ee[2] = (int)((r0 >> 16) & 255u);
            ee[3] = (int)(r0 >> 24);
            ee[4] = (int)(r1 & 255u);
            ee[5] = (int)((r1 >> 8) & 255u);
            int pp[6];
            #pragma unroll
            for (int t = 0; t < 6; ++t) pp[t] = ee[t] * BW1;
            #pragma unroll
            for (int kx = 0; kx < 3; ++kx) {
                int cq = (int)qwp[ky * 3 + kx];
                int cc = cq - cmin;
                if ((unsigned)cc < (unsigned)BW1) {
                    acc0 += band[pp[kx + 0] + cc];
                    acc1 += band[pp[kx + 1] + cc];
                    acc2 += band[pp[kx + 2] + cc];
                    acc3 += band[pp[kx + 3] + cc];
                } else {
                    acc0 += lut[(ee[kx + 0] << 8) + cq];
                    acc1 += lut[(ee[kx + 1] << 8) + cq];
                    acc2 += lut[(ee[kx + 2] << 8) + cq];
                    acc3 += lut[(ee[kx + 3] << 8) + cq];
                }
            }
        }
    }

    float bo = bias[o];
    float4 r;
    r.x = acc0 + bo; r.y = acc1 + bo; r.z = acc2 + bo; r.w = acc3 + bo;
    *(float4*)(out + (size_t)bid * 1024 + y * 32 + x0) = r;
}

extern "C" void kernel_launch(void* const* d_in, const int* in_sizes, int n_in,
                              void* d_out, int out_size, void* d_ws, size_t ws_size,
                              hipStream_t stream) {
    const float* x    = (const float*)d_in[0];
    const float* wgt  = (const float*)d_in[1];
    const float* bias = (const float*)d_in[2];
    const float* lut  = (const float*)d_in[3];
    float* out = (float*)d_out;

    const size_t T_BYTES = (size_t)32 * 64 * 256 * 48;   // 25,165,824
    if (ws_size >= T_BYTES) {
        hipLaunchKernelGGL(build_T2, dim3(256), dim3(NT), 0, stream,
                           wgt, lut, (unsigned int*)d_ws);
        hipLaunchKernelGGL(approx_main, dim3(512), dim3(NT), 0, stream,
                           x, (const unsigned int*)d_ws, bias, out);
    } else {
        hipLaunchKernelGGL(approxconv2d_v1, dim3(512), dim3(NT), 0, stream,
                           x, wgt, bias, lut, out);
    }
}